// Round 2
// baseline (2476.413 us; speedup 1.0000x reference)
//
#include <hip/hip_runtime.h>

// ---------------------------------------------------------------------------
// AttentionLayer: q=XWq+bq, k=XWk+bk, v=XWv+bv; S=qk^T (NO 1/sqrt(d) scale);
// P=softmax(S); out=PV.   B=4, L=4096, D=768, fp32 in/out.
//
// Precision strategy: hi/lo _Float16 split (Markidis) for X,W,Q,K so logits
// are accurate to ~1e-3. P,V in plain f16. All matmuls on mfma_f32_16x16x32_f16.
//
// R1 change (resubmitted R2 — prior bench was an infra container failure):
// k_attn Q-tile 32->16 rows (grid 512->1024 blocks, 4 blocks/CU,
// launch_bounds(256,4)); removed redundant 3rd barrier per KV-tile (barrier
// ordering proof: next-tile Sbuf writes occur after bar2(kt) which already
// orders all softmax reads; Pbuf/abuf rewrites occur after bar1(kt+1) which
// orders all PV reads). Occupancy was grid-limited at 23.8%.
// ---------------------------------------------------------------------------

typedef _Float16 f16;
typedef _Float16 f16x8 __attribute__((ext_vector_type(8)));
typedef _Float16 f16x4 __attribute__((ext_vector_type(4)));
typedef _Float16 f16x2 __attribute__((ext_vector_type(2)));
typedef float f32x4 __attribute__((ext_vector_type(4)));

#define NB 4
#define NL 4096
#define ND 768
#define NM (NB * NL)  // 16384 rows

__device__ __forceinline__ void split_f16(float v, f16& h, f16& l) {
    h = (f16)v;
    l = (f16)(v - (float)h);
}

// ---- convert hidden_states -> Xh, Xl (hi/lo f16), same [M][D] layout ------
__global__ __launch_bounds__(256) void k_convert_x(
    const float* __restrict__ x, f16* __restrict__ xh, f16* __restrict__ xl) {
    int i = blockIdx.x * 256 + threadIdx.x;       // group of 4 elems
    float4 v = ((const float4*)x)[i];
    float vv[4] = {v.x, v.y, v.z, v.w};
    f16x4 hv, lv;
    for (int j = 0; j < 4; ++j) {
        f16 h, l; split_f16(vv[j], h, l);
        hv[j] = h; lv[j] = l;
    }
    ((f16x4*)xh)[i] = hv;
    ((f16x4*)xl)[i] = lv;
}

// ---- transpose W [k][n] -> Wt [n][k] as hi/lo f16 (3 matrices, z picks) ---
__global__ __launch_bounds__(256) void k_convert_w(
    const float* __restrict__ Wq, const float* __restrict__ Wk,
    const float* __restrict__ Wv, f16* __restrict__ wth, f16* __restrict__ wtl) {
    __shared__ float tile[32][33];
    const float* W = blockIdx.z == 0 ? Wq : (blockIdx.z == 1 ? Wk : Wv);
    f16* th = wth + blockIdx.z * ND * ND;
    f16* tl = wtl + blockIdx.z * ND * ND;
    const int k0 = blockIdx.x * 32, n0 = blockIdx.y * 32;
    const int tx = threadIdx.x & 31, ty = threadIdx.x >> 5;  // ty 0..7
    for (int r = 0; r < 4; ++r)
        tile[r * 8 + ty][tx] = W[(k0 + r * 8 + ty) * ND + n0 + tx];
    __syncthreads();
    for (int r = 0; r < 4; ++r) {
        float v = tile[tx][r * 8 + ty];
        int n = n0 + r * 8 + ty, k = k0 + tx;
        f16 h, l; split_f16(v, h, l);
        th[n * ND + k] = h;
        tl[n * ND + k] = l;
    }
}

// ---- projection GEMM: C[M,N] = X[M,K] * W[K,N] + bias, hi/lo MFMA ---------
// z=0 -> Qh/Ql, z=1 -> Kh/Kl, z=2 -> Vt (transposed [b][d][pos], hi only)
// 128x128 tile, 4 waves in 2x2, each wave 64x64 = 4x4 frags of 16x16.
__global__ __launch_bounds__(256, 2) void k_proj(
    const f16* __restrict__ xh, const f16* __restrict__ xl,
    const f16* __restrict__ wth, const f16* __restrict__ wtl,
    const float* __restrict__ bq, const float* __restrict__ bk,
    const float* __restrict__ bv,
    f16* __restrict__ qh, f16* __restrict__ ql,
    f16* __restrict__ kh, f16* __restrict__ kl, f16* __restrict__ vt) {
    const int z = blockIdx.z;
    const f16* wh = wth + z * ND * ND;
    const f16* wl = wtl + z * ND * ND;
    const float* bias = z == 0 ? bq : (z == 1 ? bk : bv);
    const int m0 = blockIdx.x * 128, n0 = blockIdx.y * 128;

    // LDS: rows padded to 40 f16 (80B stride -> only 2-way bank aliasing=free)
    __shared__ f16 Ah[128 * 40], Al[128 * 40], Bh[128 * 40], Bl[128 * 40];

    const int t = threadIdx.x;
    const int lane = t & 63, quad = lane >> 4, l16 = lane & 15;
    const int wave = t >> 6, wm = wave >> 1, wn = wave & 1;

    f32x4 acc[4][4] = {};

    for (int kt = 0; kt < 24; ++kt) {
        const int k0 = kt * 32;
        __syncthreads();
        // stage 128x32 tiles (hi+lo of A and B) via 16B chunks
        for (int i = 0; i < 2; ++i) {
            int c = i * 256 + t;
            int row = c >> 2, kc = (c & 3) * 8;
            *(uint4*)&Ah[row * 40 + kc] = *(const uint4*)&xh[(m0 + row) * ND + k0 + kc];
            *(uint4*)&Al[row * 40 + kc] = *(const uint4*)&xl[(m0 + row) * ND + k0 + kc];
            *(uint4*)&Bh[row * 40 + kc] = *(const uint4*)&wh[(n0 + row) * ND + k0 + kc];
            *(uint4*)&Bl[row * 40 + kc] = *(const uint4*)&wl[(n0 + row) * ND + k0 + kc];
        }
        __syncthreads();
        f16x8 ah[4], al[4], bh[4], bl[4];
#pragma unroll
        for (int f = 0; f < 4; ++f) {
            int m = wm * 64 + f * 16 + l16;
            ah[f] = *(const f16x8*)&Ah[m * 40 + quad * 8];
            al[f] = *(const f16x8*)&Al[m * 40 + quad * 8];
            int n = wn * 64 + f * 16 + l16;
            bh[f] = *(const f16x8*)&Bh[n * 40 + quad * 8];
            bl[f] = *(const f16x8*)&Bl[n * 40 + quad * 8];
        }
#pragma unroll
        for (int fm = 0; fm < 4; ++fm)
#pragma unroll
            for (int fn = 0; fn < 4; ++fn) {
                f32x4 c = acc[fm][fn];
                c = __builtin_amdgcn_mfma_f32_16x16x32_f16(al[fm], bh[fn], c, 0, 0, 0);
                c = __builtin_amdgcn_mfma_f32_16x16x32_f16(ah[fm], bl[fn], c, 0, 0, 0);
                c = __builtin_amdgcn_mfma_f32_16x16x32_f16(ah[fm], bh[fn], c, 0, 0, 0);
                acc[fm][fn] = c;
            }
    }
    // epilogue: C/D layout col=lane&15, row=quad*4+reg  [verified m89/m91]
#pragma unroll
    for (int fm = 0; fm < 4; ++fm)
#pragma unroll
        for (int fn = 0; fn < 4; ++fn) {
            int col = n0 + wn * 64 + fn * 16 + l16;
            float bv_ = bias[col];
#pragma unroll
            for (int r = 0; r < 4; ++r) {
                int row = m0 + wm * 64 + fm * 16 + quad * 4 + r;
                float v = acc[fm][fn][r] + bv_;
                f16 h, l; split_f16(v, h, l);
                if (z == 0) { qh[row * ND + col] = h; ql[row * ND + col] = l; }
                else if (z == 1) { kh[row * ND + col] = h; kl[row * ND + col] = l; }
                else {
                    int b = row >> 12, pos = row & 4095;
                    vt[(b * ND + col) * NL + pos] = h;  // V^T for PV b_frags
                }
            }
        }
}

// ---- flash attention: Q-tile=16 rows/block, 4 waves split D into 192-chunks
// S partial per wave over its d-chunk -> LDS reduce -> online softmax -> PV.
// Grid (NL/16, NB) = 1024 blocks -> 4 blocks/CU (was grid-limited at 2).
// 2 barriers per KV-tile (3rd proven redundant by barrier-ordering).
__global__ __launch_bounds__(256, 4) void k_attn(
    const f16* __restrict__ qh, const f16* __restrict__ ql,
    const f16* __restrict__ kh, const f16* __restrict__ kl,
    const f16* __restrict__ vt, float* __restrict__ out) {
    const int qt = blockIdx.x, b = blockIdx.y;
    const int q0 = qt * 16;
    const int t = threadIdx.x, w = t >> 6, lane = t & 63;
    const int quad = lane >> 4, l16 = lane & 15;
    const int dw = w * 192;  // this wave's D-chunk for PV/O

    __shared__ float Sbuf[4][16][33];  // per-wave partial S (padded)
    __shared__ f16 Pbuf[16 * 40];      // P tile, row stride 40
    __shared__ float mstate[16], lstate[16], abuf[16];

    if (t < 16) { mstate[t] = -1e30f; lstate[t] = 0.f; }
    f32x4 oacc[12] = {};  // O acc: 1 row-frag x 12 col-frags (192 cols)
    __syncthreads();

    for (int kt = 0; kt < 128; ++kt) {
        const int p0 = kt * 32;
        // ---- S partial = Q[q0:q0+16, dw:dw+192] * K^T over this d-chunk ----
        f32x4 sacc[2] = {};
#pragma unroll
        for (int dk = 0; dk < 6; ++dk) {
            const int d = dw + dk * 32 + quad * 8;
            const int qrow = (b * NL + q0 + l16) * ND + d;
            f16x8 aH = *(const f16x8*)&qh[qrow];
            f16x8 aL = *(const f16x8*)&ql[qrow];
#pragma unroll
            for (int fn = 0; fn < 2; ++fn) {
                const int krow = (b * NL + p0 + fn * 16 + l16) * ND + d;
                f16x8 bH = *(const f16x8*)&kh[krow];
                f16x8 bL = *(const f16x8*)&kl[krow];
                f32x4 c = sacc[fn];
                c = __builtin_amdgcn_mfma_f32_16x16x32_f16(aL, bH, c, 0, 0, 0);
                c = __builtin_amdgcn_mfma_f32_16x16x32_f16(aH, bL, c, 0, 0, 0);
                c = __builtin_amdgcn_mfma_f32_16x16x32_f16(aH, bH, c, 0, 0, 0);
                sacc[fn] = c;
            }
        }
#pragma unroll
        for (int fn = 0; fn < 2; ++fn)
#pragma unroll
            for (int r = 0; r < 4; ++r)
                Sbuf[w][quad * 4 + r][fn * 16 + l16] = sacc[fn][r];
        __syncthreads();  // bar1: Sbuf complete

        // ---- online softmax: 256 threads cover 16 rows x 32 cols (2/thread)
        {
            const int r = t >> 4;          // 0..15
            const int c0 = (t & 15) * 2;
            float s0 = Sbuf[0][r][c0] + Sbuf[1][r][c0] +
                       Sbuf[2][r][c0] + Sbuf[3][r][c0];
            float s1 = Sbuf[0][r][c0 + 1] + Sbuf[1][r][c0 + 1] +
                       Sbuf[2][r][c0 + 1] + Sbuf[3][r][c0 + 1];
            float mx = fmaxf(s0, s1);
#pragma unroll
            for (int off = 1; off < 16; off <<= 1) mx = fmaxf(mx, __shfl_xor(mx, off, 64));
            float m_old = mstate[r];
            float m_new = fmaxf(m_old, mx);
            float p0v = __expf(s0 - m_new), p1v = __expf(s1 - m_new);
            float psum = p0v + p1v;
#pragma unroll
            for (int off = 1; off < 16; off <<= 1) psum += __shfl_xor(psum, off, 64);
            float alpha = __expf(m_old - m_new);
            if ((t & 15) == 0) {
                mstate[r] = m_new;
                lstate[r] = alpha * lstate[r] + psum;
                abuf[r] = alpha;
            }
            f16x2 pv2; pv2[0] = (f16)p0v; pv2[1] = (f16)p1v;
            *(f16x2*)&Pbuf[r * 40 + c0] = pv2;
        }
        __syncthreads();  // bar2: Pbuf/abuf complete

        // ---- rescale O by alpha, then O += P * V over this d-chunk ----
        float av[4];
#pragma unroll
        for (int r = 0; r < 4; ++r) av[r] = abuf[quad * 4 + r];
#pragma unroll
        for (int fn = 0; fn < 12; ++fn)
#pragma unroll
            for (int r = 0; r < 4; ++r) oacc[fn][r] *= av[r];

        f16x8 pa = *(const f16x8*)&Pbuf[l16 * 40 + quad * 8];
#pragma unroll
        for (int fn = 0; fn < 12; ++fn) {
            const int dcol = dw + fn * 16 + l16;
            f16x8 vb = *(const f16x8*)&vt[(b * ND + dcol) * NL + p0 + quad * 8];
            oacc[fn] = __builtin_amdgcn_mfma_f32_16x16x32_f16(pa, vb, oacc[fn], 0, 0, 0);
        }
        // no 3rd barrier: next tile's Sbuf writes are ordered after bar2(kt),
        // and Pbuf/abuf rewrites after bar1(kt+1) — both hazard-free.
    }

    // ---- epilogue: out = O / l ----
    float linv[4];
#pragma unroll
    for (int r = 0; r < 4; ++r) linv[r] = 1.f / lstate[quad * 4 + r];
#pragma unroll
    for (int fn = 0; fn < 12; ++fn) {
        int col = dw + fn * 16 + l16;
#pragma unroll
        for (int r = 0; r < 4; ++r) {
            int row = b * NL + q0 + quad * 4 + r;
            out[row * ND + col] = oacc[fn][r] * linv[r];
        }
    }
}

extern "C" void kernel_launch(void* const* d_in, const int* in_sizes, int n_in,
                              void* d_out, int out_size, void* d_ws, size_t ws_size,
                              hipStream_t stream) {
    const float* hs = (const float*)d_in[0];
    const float* Wq = (const float*)d_in[1];
    const float* bq = (const float*)d_in[2];
    const float* Wk = (const float*)d_in[3];
    const float* bk = (const float*)d_in[4];
    const float* Wv = (const float*)d_in[5];
    const float* bv = (const float*)d_in[6];
    float* out = (float*)d_out;

    char* ws = (char*)d_ws;
    size_t off = 0;
    auto alloc = [&](size_t bytes) {
        void* p = ws + off;
        off += (bytes + 255) & ~(size_t)255;
        return p;
    };
    const size_t MD = (size_t)NM * ND;  // 12,582,912
    f16* Xh = (f16*)alloc(MD * 2);
    f16* Xl = (f16*)alloc(MD * 2);
    f16* Wth = (f16*)alloc((size_t)3 * ND * ND * 2);
    f16* Wtl = (f16*)alloc((size_t)3 * ND * ND * 2);
    f16* Qh = (f16*)alloc(MD * 2);
    f16* Ql = (f16*)alloc(MD * 2);
    f16* Kh = (f16*)alloc(MD * 2);
    f16* Kl = (f16*)alloc(MD * 2);
    f16* Vt = (f16*)alloc(MD * 2);
    (void)ws_size; (void)in_sizes; (void)n_in; (void)out_size;

    k_convert_x<<<dim3(MD / 1024), 256, 0, stream>>>(hs, Xh, Xl);
    k_convert_w<<<dim3(24, 24, 3), 256, 0, stream>>>(Wq, Wk, Wv, Wth, Wtl);
    k_proj<<<dim3(NM / 128, ND / 128, 3), 256, 0, stream>>>(
        Xh, Xl, Wth, Wtl, bq, bk, bv, Qh, Ql, Kh, Kl, Vt);
    k_attn<<<dim3(NL / 16, NB), 256, 0, stream>>>(Qh, Ql, Kh, Kl, Vt, out);
}

// Round 3
// 1855.169 us; speedup vs baseline: 1.3349x; 1.3349x over previous
//
#include <hip/hip_runtime.h>

// ---------------------------------------------------------------------------
// AttentionLayer: q=XWq+bq, k=XWk+bk, v=XWv+bv; S=qk^T (NO 1/sqrt(d) scale);
// P=softmax(S); out=PV.   B=4, L=4096, D=768, fp32 in/out.
//
// Precision: hi/lo _Float16 split (Markidis) for X,W,Q,K -> logits ~1e-3.
// P,V plain f16. All matmuls mfma_f32_16x16x32_f16.
//
// R3: k_attn is L2/L3-BW-bound on K/V re-reads (R0 vs R1 natural experiment:
// time ratio == traffic ratio at constant ~8 TB/s apparent cache BW).
//  - Q-tile 32->64 rows (512-thr block, 8 waves): K/V traffic halves vs R0.
//    QK^T: waves = 4 d-groups x 2 col-halves -> Sbuf[4][64][33] = 34 KB.
//    PV: waves split D into 8 x 96-col chunks (oacc[4][6] = 96 VGPR).
//  - XCD swizzle (grid 256 = 1 block/CU): each XCD serves ONE batch's
//    contiguous q-tiles -> K/V hot window L2-resident (L3 hit -> L2 hit).
//  - V-tile loads hoisted to iteration start (latency under QK^T compute).
// ---------------------------------------------------------------------------

typedef _Float16 f16;
typedef _Float16 f16x8 __attribute__((ext_vector_type(8)));
typedef _Float16 f16x4 __attribute__((ext_vector_type(4)));
typedef float f32x4 __attribute__((ext_vector_type(4)));

#define NB 4
#define NL 4096
#define ND 768
#define NM (NB * NL)  // 16384 rows

__device__ __forceinline__ void split_f16(float v, f16& h, f16& l) {
    h = (f16)v;
    l = (f16)(v - (float)h);
}

// ---- convert hidden_states -> Xh, Xl (hi/lo f16), same [M][D] layout ------
__global__ __launch_bounds__(256) void k_convert_x(
    const float* __restrict__ x, f16* __restrict__ xh, f16* __restrict__ xl) {
    int i = blockIdx.x * 256 + threadIdx.x;       // group of 4 elems
    float4 v = ((const float4*)x)[i];
    float vv[4] = {v.x, v.y, v.z, v.w};
    f16x4 hv, lv;
    for (int j = 0; j < 4; ++j) {
        f16 h, l; split_f16(vv[j], h, l);
        hv[j] = h; lv[j] = l;
    }
    ((f16x4*)xh)[i] = hv;
    ((f16x4*)xl)[i] = lv;
}

// ---- transpose W [k][n] -> Wt [n][k] as hi/lo f16 (3 matrices, z picks) ---
__global__ __launch_bounds__(256) void k_convert_w(
    const float* __restrict__ Wq, const float* __restrict__ Wk,
    const float* __restrict__ Wv, f16* __restrict__ wth, f16* __restrict__ wtl) {
    __shared__ float tile[32][33];
    const float* W = blockIdx.z == 0 ? Wq : (blockIdx.z == 1 ? Wk : Wv);
    f16* th = wth + blockIdx.z * ND * ND;
    f16* tl = wtl + blockIdx.z * ND * ND;
    const int k0 = blockIdx.x * 32, n0 = blockIdx.y * 32;
    const int tx = threadIdx.x & 31, ty = threadIdx.x >> 5;  // ty 0..7
    for (int r = 0; r < 4; ++r)
        tile[r * 8 + ty][tx] = W[(k0 + r * 8 + ty) * ND + n0 + tx];
    __syncthreads();
    for (int r = 0; r < 4; ++r) {
        float v = tile[tx][r * 8 + ty];
        int n = n0 + r * 8 + ty, k = k0 + tx;
        f16 h, l; split_f16(v, h, l);
        th[n * ND + k] = h;
        tl[n * ND + k] = l;
    }
}

// ---- projection GEMM: C[M,N] = X[M,K] * W[K,N] + bias, hi/lo MFMA ---------
// z=0 -> Qh/Ql, z=1 -> Kh/Kl, z=2 -> Vt (transposed [b][d][pos], hi only)
// 128x128 tile, 4 waves in 2x2, each wave 64x64 = 4x4 frags of 16x16.
__global__ __launch_bounds__(256, 2) void k_proj(
    const f16* __restrict__ xh, const f16* __restrict__ xl,
    const f16* __restrict__ wth, const f16* __restrict__ wtl,
    const float* __restrict__ bq, const float* __restrict__ bk,
    const float* __restrict__ bv,
    f16* __restrict__ qh, f16* __restrict__ ql,
    f16* __restrict__ kh, f16* __restrict__ kl, f16* __restrict__ vt) {
    const int z = blockIdx.z;
    const f16* wh = wth + z * ND * ND;
    const f16* wl = wtl + z * ND * ND;
    const float* bias = z == 0 ? bq : (z == 1 ? bk : bv);
    const int m0 = blockIdx.x * 128, n0 = blockIdx.y * 128;

    // LDS: rows padded to 40 f16 (80B stride -> only 2-way bank aliasing=free)
    __shared__ f16 Ah[128 * 40], Al[128 * 40], Bh[128 * 40], Bl[128 * 40];

    const int t = threadIdx.x;
    const int lane = t & 63, quad = lane >> 4, l16 = lane & 15;
    const int wave = t >> 6, wm = wave >> 1, wn = wave & 1;

    f32x4 acc[4][4] = {};

    for (int kt = 0; kt < 24; ++kt) {
        const int k0 = kt * 32;
        __syncthreads();
        // stage 128x32 tiles (hi+lo of A and B) via 16B chunks
        for (int i = 0; i < 2; ++i) {
            int c = i * 256 + t;
            int row = c >> 2, kc = (c & 3) * 8;
            *(uint4*)&Ah[row * 40 + kc] = *(const uint4*)&xh[(m0 + row) * ND + k0 + kc];
            *(uint4*)&Al[row * 40 + kc] = *(const uint4*)&xl[(m0 + row) * ND + k0 + kc];
            *(uint4*)&Bh[row * 40 + kc] = *(const uint4*)&wh[(n0 + row) * ND + k0 + kc];
            *(uint4*)&Bl[row * 40 + kc] = *(const uint4*)&wl[(n0 + row) * ND + k0 + kc];
        }
        __syncthreads();
        f16x8 ah[4], al[4], bh[4], bl[4];
#pragma unroll
        for (int f = 0; f < 4; ++f) {
            int m = wm * 64 + f * 16 + l16;
            ah[f] = *(const f16x8*)&Ah[m * 40 + quad * 8];
            al[f] = *(const f16x8*)&Al[m * 40 + quad * 8];
            int n = wn * 64 + f * 16 + l16;
            bh[f] = *(const f16x8*)&Bh[n * 40 + quad * 8];
            bl[f] = *(const f16x8*)&Bl[n * 40 + quad * 8];
        }
#pragma unroll
        for (int fm = 0; fm < 4; ++fm)
#pragma unroll
            for (int fn = 0; fn < 4; ++fn) {
                f32x4 c = acc[fm][fn];
                c = __builtin_amdgcn_mfma_f32_16x16x32_f16(al[fm], bh[fn], c, 0, 0, 0);
                c = __builtin_amdgcn_mfma_f32_16x16x32_f16(ah[fm], bl[fn], c, 0, 0, 0);
                c = __builtin_amdgcn_mfma_f32_16x16x32_f16(ah[fm], bh[fn], c, 0, 0, 0);
                acc[fm][fn] = c;
            }
    }
    // epilogue: C/D layout col=lane&15, row=quad*4+reg  [verified m89/m91]
#pragma unroll
    for (int fm = 0; fm < 4; ++fm)
#pragma unroll
        for (int fn = 0; fn < 4; ++fn) {
            int col = n0 + wn * 64 + fn * 16 + l16;
            float bv_ = bias[col];
#pragma unroll
            for (int r = 0; r < 4; ++r) {
                int row = m0 + wm * 64 + fm * 16 + quad * 4 + r;
                float v = acc[fm][fn][r] + bv_;
                f16 h, l; split_f16(v, h, l);
                if (z == 0) { qh[row * ND + col] = h; ql[row * ND + col] = l; }
                else if (z == 1) { kh[row * ND + col] = h; kl[row * ND + col] = l; }
                else {
                    int b = row >> 12, pos = row & 4095;
                    vt[(b * ND + col) * NL + pos] = h;  // V^T for PV b_frags
                }
            }
        }
}

// ---- flash attention: Q-tile=64 rows/block, 512 threads (8 waves) ---------
// QK^T: wave = (dg, ch): dg=w>>1 owns d-chunk of 192, ch=w&1 owns 16 of the
//   32 K-cols. Partials -> Sbuf[4][64][33] -> summed in softmax phase.
// PV: wave w owns 96 output cols (dw = w*96), oacc[4][6].
// Grid: 256 blocks (1/CU), XCD-swizzled so each XCD serves one batch's
// contiguous q-tiles (K/V hot window L2-resident).
__global__ __launch_bounds__(512, 2) void k_attn(
    const f16* __restrict__ qh, const f16* __restrict__ ql,
    const f16* __restrict__ kh, const f16* __restrict__ kl,
    const f16* __restrict__ vt, float* __restrict__ out) {
    // XCD swizzle: hw assigns block wg to XCD wg%8; give XCD x the logical
    // range [x*32, x*32+32) -> one batch, contiguous q-tiles. 256%8==0: bijective.
    const int wg = blockIdx.x;
    const int swz = (wg & 7) * 32 + (wg >> 3);
    const int b = swz >> 6, qt = swz & 63;
    const int q0 = qt * 64;

    const int t = threadIdx.x, w = t >> 6, lane = t & 63;
    const int quad = lane >> 4, l16 = lane & 15;
    const int dg = w >> 1, ch = w & 1;   // QK^T role
    const int dqk = dg * 192;            // QK^T d-chunk base
    const int dw = w * 96;               // PV d-chunk base

    __shared__ float Sbuf[4][64][33];    // per-d-group partial S (padded)
    __shared__ f16 Pbuf[64 * 40];        // P tile, row stride 40
    __shared__ float mstate[64], lstate[64], abuf[64];

    if (t < 64) { mstate[t] = -1e30f; lstate[t] = 0.f; }
    f32x4 oacc[4][6] = {};               // 64 rows x 96 cols per wave
    __syncthreads();

    for (int kt = 0; kt < 128; ++kt) {
        const int p0 = kt * 32;

        // ---- hoist V loads: latency hides under QK^T compute ----
        f16x8 vb[6];
#pragma unroll
        for (int fn = 0; fn < 6; ++fn) {
            const int dcol = dw + fn * 16 + l16;
            vb[fn] = *(const f16x8*)&vt[(b * ND + dcol) * NL + p0 + quad * 8];
        }

        // ---- S partial: rows q0..q0+63, cols ch*16..+16, d in [dqk,dqk+192)
        f32x4 sacc[4] = {};
#pragma unroll
        for (int dk = 0; dk < 6; ++dk) {
            const int d = dqk + dk * 32 + quad * 8;
            const int krow = (b * NL + p0 + ch * 16 + l16) * ND + d;
            f16x8 bH = *(const f16x8*)&kh[krow];
            f16x8 bL = *(const f16x8*)&kl[krow];
#pragma unroll
            for (int fm = 0; fm < 4; ++fm) {
                const int qrow = (b * NL + q0 + fm * 16 + l16) * ND + d;
                f16x8 aH = *(const f16x8*)&qh[qrow];
                f16x8 aL = *(const f16x8*)&ql[qrow];
                f32x4 c = sacc[fm];
                c = __builtin_amdgcn_mfma_f32_16x16x32_f16(aL, bH, c, 0, 0, 0);
                c = __builtin_amdgcn_mfma_f32_16x16x32_f16(aH, bL, c, 0, 0, 0);
                c = __builtin_amdgcn_mfma_f32_16x16x32_f16(aH, bH, c, 0, 0, 0);
                sacc[fm] = c;
            }
        }
#pragma unroll
        for (int fm = 0; fm < 4; ++fm)
#pragma unroll
            for (int r = 0; r < 4; ++r)
                Sbuf[dg][fm * 16 + quad * 4 + r][ch * 16 + l16] = sacc[fm][r];
        __syncthreads();  // bar1: Sbuf complete

        // ---- online softmax: 512 threads = 64 rows x 8 lanes (4 cols each)
        {
            const int r = t >> 3;            // 0..63
            const int c0 = (t & 7) * 4;      // 0,4,...,28
            float s[4];
#pragma unroll
            for (int c = 0; c < 4; ++c)
                s[c] = Sbuf[0][r][c0 + c] + Sbuf[1][r][c0 + c] +
                       Sbuf[2][r][c0 + c] + Sbuf[3][r][c0 + c];
            float mx = fmaxf(fmaxf(s[0], s[1]), fmaxf(s[2], s[3]));
#pragma unroll
            for (int off = 1; off < 8; off <<= 1) mx = fmaxf(mx, __shfl_xor(mx, off, 64));
            float m_old = mstate[r];
            float m_new = fmaxf(m_old, mx);
            float p[4], psum = 0.f;
#pragma unroll
            for (int c = 0; c < 4; ++c) { p[c] = __expf(s[c] - m_new); psum += p[c]; }
#pragma unroll
            for (int off = 1; off < 8; off <<= 1) psum += __shfl_xor(psum, off, 64);
            float alpha = __expf(m_old - m_new);
            if ((t & 7) == 0) {
                mstate[r] = m_new;
                lstate[r] = alpha * lstate[r] + psum;
                abuf[r] = alpha;
            }
            f16x4 pv4;
#pragma unroll
            for (int c = 0; c < 4; ++c) pv4[c] = (f16)p[c];
            *(f16x4*)&Pbuf[r * 40 + c0] = pv4;
        }
        __syncthreads();  // bar2: Pbuf/abuf complete

        // ---- rescale O by alpha, then O += P * V over this wave's 96 cols --
        float av[4][4];
#pragma unroll
        for (int fm = 0; fm < 4; ++fm)
#pragma unroll
            for (int r = 0; r < 4; ++r) av[fm][r] = abuf[fm * 16 + quad * 4 + r];
#pragma unroll
        for (int fm = 0; fm < 4; ++fm)
#pragma unroll
            for (int fn = 0; fn < 6; ++fn)
#pragma unroll
                for (int r = 0; r < 4; ++r) oacc[fm][fn][r] *= av[fm][r];

        f16x8 pa[4];
#pragma unroll
        for (int fm = 0; fm < 4; ++fm)
            pa[fm] = *(const f16x8*)&Pbuf[(fm * 16 + l16) * 40 + quad * 8];
#pragma unroll
        for (int fn = 0; fn < 6; ++fn)
#pragma unroll
            for (int fm = 0; fm < 4; ++fm)
                oacc[fm][fn] = __builtin_amdgcn_mfma_f32_16x16x32_f16(pa[fm], vb[fn], oacc[fm][fn], 0, 0, 0);
        // no 3rd barrier: next tile's Sbuf writes are ordered after bar2(kt),
        // and Pbuf/abuf rewrites after bar1(kt+1) — both hazard-free.
    }

    // ---- epilogue: out = O / l ----
    float linv[4][4];
#pragma unroll
    for (int fm = 0; fm < 4; ++fm)
#pragma unroll
        for (int r = 0; r < 4; ++r) linv[fm][r] = 1.f / lstate[fm * 16 + quad * 4 + r];
#pragma unroll
    for (int fm = 0; fm < 4; ++fm)
#pragma unroll
        for (int fn = 0; fn < 6; ++fn) {
            int col = dw + fn * 16 + l16;
#pragma unroll
            for (int r = 0; r < 4; ++r) {
                int row = b * NL + q0 + fm * 16 + quad * 4 + r;
                out[row * ND + col] = oacc[fm][fn][r] * linv[fm][r];
            }
        }
}

extern "C" void kernel_launch(void* const* d_in, const int* in_sizes, int n_in,
                              void* d_out, int out_size, void* d_ws, size_t ws_size,
                              hipStream_t stream) {
    const float* hs = (const float*)d_in[0];
    const float* Wq = (const float*)d_in[1];
    const float* bq = (const float*)d_in[2];
    const float* Wk = (const float*)d_in[3];
    const float* bk = (const float*)d_in[4];
    const float* Wv = (const float*)d_in[5];
    const float* bv = (const float*)d_in[6];
    float* out = (float*)d_out;

    char* ws = (char*)d_ws;
    size_t off = 0;
    auto alloc = [&](size_t bytes) {
        void* p = ws + off;
        off += (bytes + 255) & ~(size_t)255;
        return p;
    };
    const size_t MD = (size_t)NM * ND;  // 12,582,912
    f16* Xh = (f16*)alloc(MD * 2);
    f16* Xl = (f16*)alloc(MD * 2);
    f16* Wth = (f16*)alloc((size_t)3 * ND * ND * 2);
    f16* Wtl = (f16*)alloc((size_t)3 * ND * ND * 2);
    f16* Qh = (f16*)alloc(MD * 2);
    f16* Ql = (f16*)alloc(MD * 2);
    f16* Kh = (f16*)alloc(MD * 2);
    f16* Kl = (f16*)alloc(MD * 2);
    f16* Vt = (f16*)alloc(MD * 2);
    (void)ws_size; (void)in_sizes; (void)n_in; (void)out_size;

    k_convert_x<<<dim3(MD / 1024), 256, 0, stream>>>(hs, Xh, Xl);
    k_convert_w<<<dim3(24, 24, 3), 256, 0, stream>>>(Wq, Wk, Wv, Wth, Wtl);
    k_proj<<<dim3(NM / 128, ND / 128, 3), 256, 0, stream>>>(
        Xh, Xl, Wth, Wtl, bq, bk, bv, Qh, Ql, Kh, Kl, Vt);
    k_attn<<<dim3(256), 512, 0, stream>>>(Qh, Ql, Kh, Kl, Vt, out);
}

// Round 4
// 1157.582 us; speedup vs baseline: 2.1393x; 1.6026x over previous
//
#include <hip/hip_runtime.h>

// ---------------------------------------------------------------------------
// AttentionLayer: q=XWq+bq, k=XWk+bk, v=XWv+bv; S=qk^T (NO 1/sqrt(d) scale);
// P=softmax(S); out=PV.   B=4, L=4096, D=768, fp32 in/out.
//
// Precision: hi/lo _Float16 split (Markidis) for X,W,Q; K hi-only in attn
// (R4: dropped K-lo term; logit err sigma ~0.008, absmax ~0.05 < 0.114).
// P,V plain f16. All matmuls mfma_f32_16x16x32_f16.
//
// R4: revert to R0 config (Q-tile 32, 4 waves, grid (128,4), 2 blocks/CU —
// known-good HBM pattern, FETCH ~320 MB vs R3's 3.1 GB pathology at
// 1 block/CU + swizzle). Single lever: K hi-only QK^T. Traffic model
// (R0/R1/R3 all at ~11-13 TB/s apparent L2 BW): per-block-iter
// Q96+K96+V48=240 KB -> Q96+K48+V48=192 KB (-20%); QK^T MFMA 3->2.
// ---------------------------------------------------------------------------

typedef _Float16 f16;
typedef _Float16 f16x8 __attribute__((ext_vector_type(8)));
typedef _Float16 f16x4 __attribute__((ext_vector_type(4)));
typedef float f32x4 __attribute__((ext_vector_type(4)));

#define NB 4
#define NL 4096
#define ND 768
#define NM (NB * NL)  // 16384 rows

__device__ __forceinline__ void split_f16(float v, f16& h, f16& l) {
    h = (f16)v;
    l = (f16)(v - (float)h);
}

// ---- convert hidden_states -> Xh, Xl (hi/lo f16), same [M][D] layout ------
__global__ __launch_bounds__(256) void k_convert_x(
    const float* __restrict__ x, f16* __restrict__ xh, f16* __restrict__ xl) {
    int i = blockIdx.x * 256 + threadIdx.x;       // group of 4 elems
    float4 v = ((const float4*)x)[i];
    float vv[4] = {v.x, v.y, v.z, v.w};
    f16x4 hv, lv;
    for (int j = 0; j < 4; ++j) {
        f16 h, l; split_f16(vv[j], h, l);
        hv[j] = h; lv[j] = l;
    }
    ((f16x4*)xh)[i] = hv;
    ((f16x4*)xl)[i] = lv;
}

// ---- transpose W [k][n] -> Wt [n][k] as hi/lo f16 (3 matrices, z picks) ---
__global__ __launch_bounds__(256) void k_convert_w(
    const float* __restrict__ Wq, const float* __restrict__ Wk,
    const float* __restrict__ Wv, f16* __restrict__ wth, f16* __restrict__ wtl) {
    __shared__ float tile[32][33];
    const float* W = blockIdx.z == 0 ? Wq : (blockIdx.z == 1 ? Wk : Wv);
    f16* th = wth + blockIdx.z * ND * ND;
    f16* tl = wtl + blockIdx.z * ND * ND;
    const int k0 = blockIdx.x * 32, n0 = blockIdx.y * 32;
    const int tx = threadIdx.x & 31, ty = threadIdx.x >> 5;  // ty 0..7
    for (int r = 0; r < 4; ++r)
        tile[r * 8 + ty][tx] = W[(k0 + r * 8 + ty) * ND + n0 + tx];
    __syncthreads();
    for (int r = 0; r < 4; ++r) {
        float v = tile[tx][r * 8 + ty];
        int n = n0 + r * 8 + ty, k = k0 + tx;
        f16 h, l; split_f16(v, h, l);
        th[n * ND + k] = h;
        tl[n * ND + k] = l;
    }
}

// ---- projection GEMM: C[M,N] = X[M,K] * W[K,N] + bias, hi/lo MFMA ---------
// z=0 -> Qh/Ql, z=1 -> Kh (hi only), z=2 -> Vt (transposed [b][d][pos], hi)
// 128x128 tile, 4 waves in 2x2, each wave 64x64 = 4x4 frags of 16x16.
__global__ __launch_bounds__(256, 2) void k_proj(
    const f16* __restrict__ xh, const f16* __restrict__ xl,
    const f16* __restrict__ wth, const f16* __restrict__ wtl,
    const float* __restrict__ bq, const float* __restrict__ bk,
    const float* __restrict__ bv,
    f16* __restrict__ qh, f16* __restrict__ ql,
    f16* __restrict__ kh, f16* __restrict__ vt) {
    const int z = blockIdx.z;
    const f16* wh = wth + z * ND * ND;
    const f16* wl = wtl + z * ND * ND;
    const float* bias = z == 0 ? bq : (z == 1 ? bk : bv);
    const int m0 = blockIdx.x * 128, n0 = blockIdx.y * 128;

    // LDS: rows padded to 40 f16 (80B stride -> only 2-way bank aliasing=free)
    __shared__ f16 Ah[128 * 40], Al[128 * 40], Bh[128 * 40], Bl[128 * 40];

    const int t = threadIdx.x;
    const int lane = t & 63, quad = lane >> 4, l16 = lane & 15;
    const int wave = t >> 6, wm = wave >> 1, wn = wave & 1;

    f32x4 acc[4][4] = {};

    for (int kt = 0; kt < 24; ++kt) {
        const int k0 = kt * 32;
        __syncthreads();
        // stage 128x32 tiles (hi+lo of A and B) via 16B chunks
        for (int i = 0; i < 2; ++i) {
            int c = i * 256 + t;
            int row = c >> 2, kc = (c & 3) * 8;
            *(uint4*)&Ah[row * 40 + kc] = *(const uint4*)&xh[(m0 + row) * ND + k0 + kc];
            *(uint4*)&Al[row * 40 + kc] = *(const uint4*)&xl[(m0 + row) * ND + k0 + kc];
            *(uint4*)&Bh[row * 40 + kc] = *(const uint4*)&wh[(n0 + row) * ND + k0 + kc];
            *(uint4*)&Bl[row * 40 + kc] = *(const uint4*)&wl[(n0 + row) * ND + k0 + kc];
        }
        __syncthreads();
        f16x8 ah[4], al[4], bh[4], bl[4];
#pragma unroll
        for (int f = 0; f < 4; ++f) {
            int m = wm * 64 + f * 16 + l16;
            ah[f] = *(const f16x8*)&Ah[m * 40 + quad * 8];
            al[f] = *(const f16x8*)&Al[m * 40 + quad * 8];
            int n = wn * 64 + f * 16 + l16;
            bh[f] = *(const f16x8*)&Bh[n * 40 + quad * 8];
            bl[f] = *(const f16x8*)&Bl[n * 40 + quad * 8];
        }
#pragma unroll
        for (int fm = 0; fm < 4; ++fm)
#pragma unroll
            for (int fn = 0; fn < 4; ++fn) {
                f32x4 c = acc[fm][fn];
                c = __builtin_amdgcn_mfma_f32_16x16x32_f16(al[fm], bh[fn], c, 0, 0, 0);
                c = __builtin_amdgcn_mfma_f32_16x16x32_f16(ah[fm], bl[fn], c, 0, 0, 0);
                c = __builtin_amdgcn_mfma_f32_16x16x32_f16(ah[fm], bh[fn], c, 0, 0, 0);
                acc[fm][fn] = c;
            }
    }
    // epilogue: C/D layout col=lane&15, row=quad*4+reg  [verified m89/m91]
#pragma unroll
    for (int fm = 0; fm < 4; ++fm)
#pragma unroll
        for (int fn = 0; fn < 4; ++fn) {
            int col = n0 + wn * 64 + fn * 16 + l16;
            float bv_ = bias[col];
#pragma unroll
            for (int r = 0; r < 4; ++r) {
                int row = m0 + wm * 64 + fm * 16 + quad * 4 + r;
                float v = acc[fm][fn][r] + bv_;
                f16 h, l; split_f16(v, h, l);
                if (z == 0) { qh[row * ND + col] = h; ql[row * ND + col] = l; }
                else if (z == 1) { kh[row * ND + col] = h; }  // K hi only
                else {
                    int b = row >> 12, pos = row & 4095;
                    vt[(b * ND + col) * NL + pos] = h;  // V^T for PV b_frags
                }
            }
        }
}

// ---- flash attention: Q-tile=32 rows/block, 4 waves split D into 192-chunks
// S partial per wave over its d-chunk -> LDS reduce -> online softmax -> PV.
// QK^T terms: aL*bH + aH*bH (K hi-only; K-lo dropped, err sigma ~0.008 logit)
__global__ __launch_bounds__(256, 2) void k_attn(
    const f16* __restrict__ qh, const f16* __restrict__ ql,
    const f16* __restrict__ kh,
    const f16* __restrict__ vt, float* __restrict__ out) {
    const int qt = blockIdx.x, b = blockIdx.y;
    const int q0 = qt * 32;
    const int t = threadIdx.x, w = t >> 6, lane = t & 63;
    const int quad = lane >> 4, l16 = lane & 15;
    const int dw = w * 192;  // this wave's D-chunk for PV/O

    __shared__ float Sbuf[4][32][33];  // per-wave partial S (padded)
    __shared__ f16 Pbuf[32 * 40];      // P tile, row stride 40
    __shared__ float mstate[32], lstate[32], abuf[32];

    if (t < 32) { mstate[t] = -1e30f; lstate[t] = 0.f; }
    f32x4 oacc[2][12] = {};  // O acc: 2 row-frags x 12 col-frags (192 cols)
    __syncthreads();

    for (int kt = 0; kt < 128; ++kt) {
        const int p0 = kt * 32;
        // ---- S partial = Q[q0:q0+32, dw:dw+192] * K^T over this d-chunk ----
        f32x4 sacc[2][2] = {};
#pragma unroll
        for (int dk = 0; dk < 6; ++dk) {
            const int d = dw + dk * 32 + quad * 8;
            f16x8 aH[2], aL[2], bH[2];
#pragma unroll
            for (int f = 0; f < 2; ++f) {
                const int qrow = (b * NL + q0 + f * 16 + l16) * ND + d;
                aH[f] = *(const f16x8*)&qh[qrow];
                aL[f] = *(const f16x8*)&ql[qrow];
                const int krow = (b * NL + p0 + f * 16 + l16) * ND + d;
                bH[f] = *(const f16x8*)&kh[krow];
            }
#pragma unroll
            for (int fm = 0; fm < 2; ++fm)
#pragma unroll
                for (int fn = 0; fn < 2; ++fn) {
                    f32x4 c = sacc[fm][fn];
                    c = __builtin_amdgcn_mfma_f32_16x16x32_f16(aL[fm], bH[fn], c, 0, 0, 0);
                    c = __builtin_amdgcn_mfma_f32_16x16x32_f16(aH[fm], bH[fn], c, 0, 0, 0);
                    sacc[fm][fn] = c;
                }
        }
#pragma unroll
        for (int fm = 0; fm < 2; ++fm)
#pragma unroll
            for (int fn = 0; fn < 2; ++fn)
#pragma unroll
                for (int r = 0; r < 4; ++r)
                    Sbuf[w][fm * 16 + quad * 4 + r][fn * 16 + l16] = sacc[fm][fn][r];
        __syncthreads();  // bar1: Sbuf complete

        // ---- online softmax: wave w owns rows 8w..8w+7 (8 lanes per row) ----
        {
            const int r = w * 8 + (lane >> 3);
            const int c0 = (lane & 7) * 4;
            float s[4];
#pragma unroll
            for (int c = 0; c < 4; ++c)
                s[c] = Sbuf[0][r][c0 + c] + Sbuf[1][r][c0 + c] +
                       Sbuf[2][r][c0 + c] + Sbuf[3][r][c0 + c];
            float mx = fmaxf(fmaxf(s[0], s[1]), fmaxf(s[2], s[3]));
#pragma unroll
            for (int off = 1; off < 8; off <<= 1) mx = fmaxf(mx, __shfl_xor(mx, off, 64));
            float m_old = mstate[r];
            float m_new = fmaxf(m_old, mx);
            float p[4], psum = 0.f;
#pragma unroll
            for (int c = 0; c < 4; ++c) { p[c] = __expf(s[c] - m_new); psum += p[c]; }
#pragma unroll
            for (int off = 1; off < 8; off <<= 1) psum += __shfl_xor(psum, off, 64);
            float alpha = __expf(m_old - m_new);
            if ((lane & 7) == 0) {
                mstate[r] = m_new;
                lstate[r] = alpha * lstate[r] + psum;
                abuf[r] = alpha;
            }
            f16x4 pv4;
#pragma unroll
            for (int c = 0; c < 4; ++c) pv4[c] = (f16)p[c];
            *(f16x4*)&Pbuf[r * 40 + c0] = pv4;
        }
        __syncthreads();  // bar2: Pbuf/abuf complete

        // ---- rescale O by alpha, then O += P * V over this d-chunk ----
        float av[2][4];
#pragma unroll
        for (int fm = 0; fm < 2; ++fm)
#pragma unroll
            for (int r = 0; r < 4; ++r) av[fm][r] = abuf[fm * 16 + quad * 4 + r];
#pragma unroll
        for (int fm = 0; fm < 2; ++fm)
#pragma unroll
            for (int fn = 0; fn < 12; ++fn)
#pragma unroll
                for (int r = 0; r < 4; ++r) oacc[fm][fn][r] *= av[fm][r];

        f16x8 pa[2];
#pragma unroll
        for (int fm = 0; fm < 2; ++fm)
            pa[fm] = *(const f16x8*)&Pbuf[(fm * 16 + l16) * 40 + quad * 8];
#pragma unroll
        for (int fn = 0; fn < 12; ++fn) {
            const int dcol = dw + fn * 16 + l16;
            f16x8 vb = *(const f16x8*)&vt[(b * ND + dcol) * NL + p0 + quad * 8];
#pragma unroll
            for (int fm = 0; fm < 2; ++fm)
                oacc[fm][fn] = __builtin_amdgcn_mfma_f32_16x16x32_f16(pa[fm], vb, oacc[fm][fn], 0, 0, 0);
        }
        // no 3rd barrier: next tile's Sbuf writes are ordered after bar2(kt),
        // and Pbuf/abuf rewrites after bar1(kt+1) — both hazard-free.
    }

    // ---- epilogue: out = O / l ----
    float linv[2][4];
#pragma unroll
    for (int fm = 0; fm < 2; ++fm)
#pragma unroll
        for (int r = 0; r < 4; ++r) linv[fm][r] = 1.f / lstate[fm * 16 + quad * 4 + r];
#pragma unroll
    for (int fm = 0; fm < 2; ++fm)
#pragma unroll
        for (int fn = 0; fn < 12; ++fn) {
            int col = dw + fn * 16 + l16;
#pragma unroll
            for (int r = 0; r < 4; ++r) {
                int row = b * NL + q0 + fm * 16 + quad * 4 + r;
                out[row * ND + col] = oacc[fm][fn][r] * linv[fm][r];
            }
        }
}

extern "C" void kernel_launch(void* const* d_in, const int* in_sizes, int n_in,
                              void* d_out, int out_size, void* d_ws, size_t ws_size,
                              hipStream_t stream) {
    const float* hs = (const float*)d_in[0];
    const float* Wq = (const float*)d_in[1];
    const float* bq = (const float*)d_in[2];
    const float* Wk = (const float*)d_in[3];
    const float* bk = (const float*)d_in[4];
    const float* Wv = (const float*)d_in[5];
    const float* bv = (const float*)d_in[6];
    float* out = (float*)d_out;

    char* ws = (char*)d_ws;
    size_t off = 0;
    auto alloc = [&](size_t bytes) {
        void* p = ws + off;
        off += (bytes + 255) & ~(size_t)255;
        return p;
    };
    const size_t MD = (size_t)NM * ND;  // 12,582,912
    f16* Xh = (f16*)alloc(MD * 2);
    f16* Xl = (f16*)alloc(MD * 2);
    f16* Wth = (f16*)alloc((size_t)3 * ND * ND * 2);
    f16* Wtl = (f16*)alloc((size_t)3 * ND * ND * 2);
    f16* Qh = (f16*)alloc(MD * 2);
    f16* Ql = (f16*)alloc(MD * 2);
    f16* Kh = (f16*)alloc(MD * 2);
    f16* Vt = (f16*)alloc(MD * 2);
    (void)ws_size; (void)in_sizes; (void)n_in; (void)out_size;

    k_convert_x<<<dim3(MD / 1024), 256, 0, stream>>>(hs, Xh, Xl);
    k_convert_w<<<dim3(24, 24, 3), 256, 0, stream>>>(Wq, Wk, Wv, Wth, Wtl);
    k_proj<<<dim3(NM / 128, ND / 128, 3), 256, 0, stream>>>(
        Xh, Xl, Wth, Wtl, bq, bk, bv, Qh, Ql, Kh, Vt);
    k_attn<<<dim3(NL / 32, NB), 256, 0, stream>>>(Qh, Ql, Kh, Vt, out);
}